// Round 9
// baseline (201.483 us; speedup 1.0000x reference)
//
#include <hip/hip_runtime.h>
#include <cmath>

#define H     256
#define H3    768
#define L     32
#define STEPS 20
#define VOUT  74
#define NP    16            // participant WGs
#define HW    16            // h rows per WG
#define ROWS  48            // gh rows per WG (3 gates x 16)

// ---- workspace layout (32-bit word offsets) ----
#define WS_EP    0                        // int epoch counter (own 64B line)
#define WS_HB    16                       // float [2][256] h double buffer
#define WS_EGI   528                      // float [NP][L][48]
#define WS_DGI   (528 + NP * L * ROWS)    // float [NP][VOUT][48] -> 25104

__device__ __forceinline__ float sigmoidf_(float x) {
    return 1.0f / (1.0f + expf(-x));
}

// global gh-row for local row lr (0..47) of role w
__device__ __forceinline__ int growf(int w, int lr) {
    int j = w * HW + (lr & 15);
    return (lr < 16) ? j : (lr < 32 ? H + j : 2 * H + j);
}

// Prep: zero epoch + h buffers; precompute input-side gate projections into
// consumer-blocked layout [role][item][48]. One wave per Wih row, 8-item reuse.
__global__ void prep(const int*   __restrict__ enc_input,
                     const float* __restrict__ enc_emb,
                     const float* __restrict__ encWih,
                     const float* __restrict__ enc_bih,
                     const float* __restrict__ dec_emb,
                     const float* __restrict__ decWih,
                     const float* __restrict__ dec_bih,
                     float* __restrict__ ws) {
    if (blockIdx.x == 0) {
        for (int k = threadIdx.x; k < 528; k += 256) ((int*)ws)[k] = 0;
    }
    int wid  = blockIdx.x * 4 + (threadIdx.x >> 6);
    int lane = threadIdx.x & 63;

    int j, i0, nIt; const float* W; const float* b; bool isEnc;
    if (wid < 3072) {                 // enc: 768 rows x 4 item-groups of 8
        j = wid >> 2; i0 = (wid & 3) * 8; nIt = 8;
        W = encWih; b = enc_bih; isEnc = true;
    } else {                          // dec: 768 rows x 10 item-groups of 8
        int w2 = wid - 3072;
        if (w2 >= 7680) return;
        j = w2 / 10; i0 = (w2 % 10) * 8;
        nIt = (VOUT - i0 < 8) ? (VOUT - i0) : 8;
        W = decWih; b = dec_bih; isEnc = false;
    }
    float4 wv = ((const float4*)(W + j * H))[lane];
    float bj = b[j];
    int wOwn = (j & 255) >> 4;                 // consumer role
    int lr   = (j >> 8) * 16 + (j & 15);       // local row within role

    for (int ii = 0; ii < nIt; ++ii) {
        int item = i0 + ii;
        const float* x = isEnc ? (enc_emb + enc_input[item] * H)
                               : (dec_emb + item * H);
        float4 xv = ((const float4*)x)[lane];
        float s = fmaf(wv.x, xv.x, fmaf(wv.y, xv.y, fmaf(wv.z, xv.z, wv.w * xv.w)));
        #pragma unroll
        for (int m = 1; m < 64; m <<= 1) s += __shfl_xor(s, m);
        if (lane == 0) {
            float* op = isEnc
                ? ws + WS_EGI + (wOwn * L + item) * ROWS + lr
                : ws + WS_DGI + (wOwn * VOUT + item) * ROWS + lr;
            *op = s + bj;
        }
    }
}

// Sequential phase: 16 WGs; Whh + fc_W in registers; exchange via
// {agent stores -> vmcnt(0) release -> one epoch atomic_add} per WG,
// single broadcast epoch poll + coalesced bulk h load per consumer.
__global__ __launch_bounds__(256, 1) void gru_seq(
        const float* __restrict__ enc_Whh, const float* __restrict__ enc_bhh,
        const float* __restrict__ dec_Whh, const float* __restrict__ dec_bhh,
        const float* __restrict__ fc_W,    const float* __restrict__ fc_b,
        float* __restrict__ ws, int* __restrict__ out) {
    __shared__ __align__(16) float hl[1040];   // 4 bank-shifted copies (stride 260)
    __shared__ float fb[VOUT];
    __shared__ float gh_l[ROWS];
    __shared__ float egi_l[L * ROWS];          // [32][48]
    __shared__ float dgi_l[VOUT * ROWS];       // [74][48]
    __shared__ float log_l[VOUT];
    __shared__ int   s_tok, s_done;

    const int t = threadIdx.x;
    const int w = blockIdx.x;
    int* ep = (int*)ws + WS_EP;
    unsigned* hb = (unsigned*)(ws + WS_HB);

    if (t == 0) { s_done = 0; s_tok = 2; }      // BOS=2
    if (w == 0 && t < STEPS) out[t] = 0;
    if (t < VOUT) fb[t] = fc_b[t];
    for (int idx = t; idx < L * ROWS; idx += 256)
        egi_l[idx] = ws[WS_EGI + w * (L * ROWS) + idx];
    for (int idx = t; idx < VOUT * ROWS; idx += 256)
        dgi_l[idx] = ws[WS_DGI + w * (VOUT * ROWS) + idx];

    // Whh slices (matvec workers t in [64,256): 4 threads per gh row)
    const int m  = t - 64;
    const int p  = t & 3;                 // k-chunk (64 floats each)
    const int lr = (t >= 64) ? (m >> 2) : 0;
    const int g  = growf(w, lr);
    float4 wE[16], wD[16];
    float bhhE = 0.f, bhhD = 0.f;
    if (t >= 64) {
        const float* eb = enc_Whh + g * H + p * 64;
        const float* db = dec_Whh + g * H + p * 64;
        #pragma unroll
        for (int i = 0; i < 16; ++i) {
            wE[i] = *(const float4*)(eb + 4 * i);
            wD[i] = *(const float4*)(db + 4 * i);
        }
        if (p == 0) { bhhE = enc_bhh[g]; bhhD = dec_bhh[g]; }
    }

    // fc_W in registers: primary row t>>2, chunk t&3; secondary 64+(t>>2) for t<40
    const int rF = t >> 2;
    float4 wF[16], wF2[16];
    {
        const float* fp = fc_W + rF * H + p * 64;
        #pragma unroll
        for (int i = 0; i < 16; ++i) wF[i] = *(const float4*)(fp + 4 * i);
        if (t < 40) {
            const float* fp2 = fc_W + (64 + rF) * H + p * 64;
            #pragma unroll
            for (int i = 0; i < 16; ++i) wF2[i] = *(const float4*)(fp2 + 4 * i);
        }
    }

    int tok = 2;  // BOS
    for (int s = 0; s <= L + STEPS; ++s) {      // 0..52
        // ---- wait for h^(s): ALL threads poll the single epoch word ----
        if (s > 0) {
            int target = NP * s;
            int e = __hip_atomic_load(ep, __ATOMIC_RELAXED,
                                      __HIP_MEMORY_SCOPE_AGENT);
            while (e < target) {
                __builtin_amdgcn_s_sleep(1);
                e = __hip_atomic_load(ep, __ATOMIC_RELAXED,
                                      __HIP_MEMORY_SCOPE_AGENT);
            }
        }
        // ---- bulk coalesced agent-scope load of h^(s) ----
        {
            unsigned u = __hip_atomic_load(hb + (s & 1) * H + t,
                                           __ATOMIC_RELAXED,
                                           __HIP_MEMORY_SCOPE_AGENT);
            float hv = __uint_as_float(u);
            hl[t] = hv; hl[260 + t] = hv; hl[520 + t] = hv; hl[780 + t] = hv;
        }
        __syncthreads();

        const bool dec_out = (s >= L + 1);
        if (dec_out) {
            // ---- logits from registers (2 independent FMA chains) ----
            const float* hb2 = hl + p * 324;
            float a0 = 0.f, a1 = 0.f;
            #pragma unroll
            for (int i = 0; i < 16; i += 2) {
                float4 h4a = *(const float4*)(hb2 + 4 * i);
                float4 h4b = *(const float4*)(hb2 + 4 * i + 4);
                a0 = fmaf(wF[i].x, h4a.x, fmaf(wF[i].y, h4a.y,
                      fmaf(wF[i].z, h4a.z, fmaf(wF[i].w, h4a.w, a0))));
                a1 = fmaf(wF[i+1].x, h4b.x, fmaf(wF[i+1].y, h4b.y,
                      fmaf(wF[i+1].z, h4b.z, fmaf(wF[i+1].w, h4b.w, a1))));
            }
            float a = a0 + a1;
            a += __shfl_xor(a, 1); a += __shfl_xor(a, 2);
            if (p == 0) log_l[rF] = a + fb[rF];
            if (t < 40) {
                float b0 = 0.f, b1 = 0.f;
                #pragma unroll
                for (int i = 0; i < 16; i += 2) {
                    float4 h4a = *(const float4*)(hb2 + 4 * i);
                    float4 h4b = *(const float4*)(hb2 + 4 * i + 4);
                    b0 = fmaf(wF2[i].x, h4a.x, fmaf(wF2[i].y, h4a.y,
                          fmaf(wF2[i].z, h4a.z, fmaf(wF2[i].w, h4a.w, b0))));
                    b1 = fmaf(wF2[i+1].x, h4b.x, fmaf(wF2[i+1].y, h4b.y,
                          fmaf(wF2[i+1].z, h4b.z, fmaf(wF2[i+1].w, h4b.w, b1))));
                }
                float a2 = b0 + b1;
                a2 += __shfl_xor(a2, 1); a2 += __shfl_xor(a2, 2);
                if (p == 0) log_l[64 + rF] = a2 + fb[64 + rF];
            }
            __syncthreads();
        }

        // ---- wave0: argmax  ||  waves1-3: GRU matvec (tok-independent) ----
        if (t < 64) {
            if (dec_out) {
                float v = log_l[t]; int bi = t;
                if (t < VOUT - 64) {
                    float v2 = log_l[64 + t];
                    if (v2 > v) { v = v2; bi = 64 + t; }
                }
                #pragma unroll
                for (int mm = 1; mm < 64; mm <<= 1) {
                    float ov = __shfl_xor(v, mm);
                    int   ob = __shfl_xor(bi, mm);
                    if (ov > v || (ov == v && ob < bi)) { v = ov; bi = ob; }
                }
                if (t == 0) {
                    bool eos = (bi == 3);                    // EOS=3
                    if (w == 0 && !eos) out[s - (L + 1)] = bi;
                    s_tok = bi;
                    if (eos) s_done = 1;
                }
            }
        } else {
            float acc0 = (s < L) ? bhhE : bhhD, acc1 = 0.f;
            const float* hb3 = hl + p * 324;     // copy p, k-offset p*64
            if (s < L) {
                #pragma unroll
                for (int i = 0; i < 16; i += 2) {
                    float4 h4a = *(const float4*)(hb3 + 4 * i);
                    float4 h4b = *(const float4*)(hb3 + 4 * i + 4);
                    acc0 = fmaf(wE[i].x, h4a.x, fmaf(wE[i].y, h4a.y,
                           fmaf(wE[i].z, h4a.z, fmaf(wE[i].w, h4a.w, acc0))));
                    acc1 = fmaf(wE[i+1].x, h4b.x, fmaf(wE[i+1].y, h4b.y,
                           fmaf(wE[i+1].z, h4b.z, fmaf(wE[i+1].w, h4b.w, acc1))));
                }
            } else {
                #pragma unroll
                for (int i = 0; i < 16; i += 2) {
                    float4 h4a = *(const float4*)(hb3 + 4 * i);
                    float4 h4b = *(const float4*)(hb3 + 4 * i + 4);
                    acc0 = fmaf(wD[i].x, h4a.x, fmaf(wD[i].y, h4a.y,
                           fmaf(wD[i].z, h4a.z, fmaf(wD[i].w, h4a.w, acc0))));
                    acc1 = fmaf(wD[i+1].x, h4b.x, fmaf(wD[i+1].y, h4b.y,
                           fmaf(wD[i+1].z, h4b.z, fmaf(wD[i+1].w, h4b.w, acc1))));
                }
            }
            float acc = acc0 + acc1;
            acc += __shfl_xor(acc, 1);
            acc += __shfl_xor(acc, 2);
            if (p == 0) gh_l[m >> 2] = acc;
        }
        __syncthreads();

        if (dec_out) {
            tok = s_tok;
            if (s_done || s == L + STEPS) break;
        }

        // ---- gates -> h^(s+1): data stores, vmcnt release, ONE epoch add ----
        if (t < HW) {
            const float* gi = (s < L) ? (egi_l + s * ROWS) : (dgi_l + tok * ROWS);
            float r = sigmoidf_(gi[t]      + gh_l[t]);
            float z = sigmoidf_(gi[16 + t] + gh_l[16 + t]);
            float n = tanhf    (gi[32 + t] + r * gh_l[32 + t]);
            float hn = (1.f - z) * n + z * hl[w * HW + t];
            __hip_atomic_store(hb + ((s + 1) & 1) * H + w * HW + t,
                               __float_as_uint(hn),
                               __ATOMIC_RELAXED, __HIP_MEMORY_SCOPE_AGENT);
            asm volatile("s_waitcnt vmcnt(0)" ::: "memory");   // release: ACKed
            if (t == 0)
                __hip_atomic_fetch_add(ep, 1, __ATOMIC_RELAXED,
                                       __HIP_MEMORY_SCOPE_AGENT);
        }
        // no trailing barrier: cross-WG ordering rides on the epoch counter;
        // intra-WG LDS hazards are covered by the per-iteration barriers.
    }
}

extern "C" void kernel_launch(void* const* d_in, const int* in_sizes, int n_in,
                              void* d_out, int out_size, void* d_ws, size_t ws_size,
                              hipStream_t stream) {
    const int*   enc_input = (const int*)  d_in[0];
    const float* enc_emb   = (const float*)d_in[1];
    const float* enc_Wih   = (const float*)d_in[2];
    const float* enc_Whh   = (const float*)d_in[3];
    const float* enc_bih   = (const float*)d_in[4];
    const float* enc_bhh   = (const float*)d_in[5];
    const float* dec_emb   = (const float*)d_in[6];
    const float* dec_Wih   = (const float*)d_in[7];
    const float* dec_Whh   = (const float*)d_in[8];
    const float* dec_bih   = (const float*)d_in[9];
    const float* dec_bhh   = (const float*)d_in[10];
    const float* fc_W      = (const float*)d_in[11];
    const float* fc_b      = (const float*)d_in[12];
    float* ws  = (float*)d_ws;
    int*  outp = (int*)d_out;

    // prep: 3072 enc + 7680 dec wave-tasks, 4 waves/block
    hipLaunchKernelGGL(prep, dim3(2688), dim3(256), 0, stream,
                       enc_input, enc_emb, enc_Wih, enc_bih,
                       dec_emb, dec_Wih, dec_bih, ws);
    hipLaunchKernelGGL(gru_seq, dim3(NP), dim3(256), 0, stream,
                       enc_Whh, enc_bhh, dec_Whh, dec_bhh, fc_W, fc_b,
                       ws, outp);
}

// Round 10
// 146.797 us; speedup vs baseline: 1.3725x; 1.3725x over previous
//
#include <hip/hip_runtime.h>
#include <cmath>

#define H     256
#define H3    768
#define L     32
#define STEPS 20
#define VOUT  74
#define NP    16            // participant WGs
#define HW    16            // h units per WG
#define ROWS  48            // gh rows per WG (3 gates x 16)

// ---- workspace layout (32-bit word offsets) ----
#define WS_HX    0                        // u64 [2][256] packed (val<<32|tag)
#define WS_EGI   1024                     // float [NP][L][48]
#define WS_DGI   (1024 + NP * L * ROWS)   // float [NP][VOUT][48] -> 25600

__device__ __forceinline__ float sigmoidf_(float x) {
    return 1.0f / (1.0f + expf(-x));
}

// Prep: zero exchange tags; precompute input-side gate projections into the
// consumer-blocked layout [role][item][48]. One wave per Wih row, 8-item reuse.
__global__ void prep(const int*   __restrict__ enc_input,
                     const float* __restrict__ enc_emb,
                     const float* __restrict__ encWih,
                     const float* __restrict__ enc_bih,
                     const float* __restrict__ dec_emb,
                     const float* __restrict__ decWih,
                     const float* __restrict__ dec_bih,
                     float* __restrict__ ws) {
    if (blockIdx.x == 0) {
        for (int k = threadIdx.x; k < 1024; k += 256) ((int*)ws)[k] = 0;
    }
    int wid  = blockIdx.x * 4 + (threadIdx.x >> 6);
    int lane = threadIdx.x & 63;

    int j, i0, nIt; const float* W; const float* b; bool isEnc;
    if (wid < 3072) {                 // enc: 768 rows x 4 item-groups of 8
        j = wid >> 2; i0 = (wid & 3) * 8; nIt = 8;
        W = encWih; b = enc_bih; isEnc = true;
    } else {                          // dec: 768 rows x 10 item-groups of 8
        int w2 = wid - 3072;
        if (w2 >= 7680) return;
        j = w2 / 10; i0 = (w2 % 10) * 8;
        nIt = (VOUT - i0 < 8) ? (VOUT - i0) : 8;
        W = decWih; b = dec_bih; isEnc = false;
    }
    float4 wv = ((const float4*)(W + j * H))[lane];
    float bj = b[j];
    int wOwn = (j & 255) >> 4;                 // consumer role
    int lr   = (j >> 8) * 16 + (j & 15);       // gate*16 + unit%16

    for (int ii = 0; ii < nIt; ++ii) {
        int item = i0 + ii;
        const float* x = isEnc ? (enc_emb + enc_input[item] * H)
                               : (dec_emb + item * H);
        float4 xv = ((const float4*)x)[lane];
        float s = fmaf(wv.x, xv.x, fmaf(wv.y, xv.y, fmaf(wv.z, xv.z, wv.w * xv.w)));
        #pragma unroll
        for (int m = 1; m < 64; m <<= 1) s += __shfl_xor(s, m);
        if (lane == 0) {
            float* op = isEnc
                ? ws + WS_EGI + (wOwn * L + item) * ROWS + lr
                : ws + WS_DGI + (wOwn * VOUT + item) * ROWS + lr;
            *op = s + bj;
        }
    }
}

// Sequential phase: 16 WGs. Layout: thread (u = t>>4, sub = t&15) owns all 3
// gate rows of unit u over k-chunk [16*sub, 16*sub+16). Gates computed fully
// in-register by lane sub==0 right after a 16-lane shuffle reduce; tagged
// (val,tag) 8B agent store issues immediately (no gh LDS, no extra barrier).
__global__ __launch_bounds__(256, 1) void gru_seq(
        const float* __restrict__ enc_Whh, const float* __restrict__ enc_bhh,
        const float* __restrict__ dec_Whh, const float* __restrict__ dec_bhh,
        const float* __restrict__ fc_W,    const float* __restrict__ fc_b,
        float* __restrict__ ws, int* __restrict__ out) {
    __shared__ __align__(16) float hl[1040];   // 4 bank-shifted copies (stride 260)
    __shared__ float fb[VOUT];
    __shared__ float egi_l[L * ROWS];          // [32][48]
    __shared__ float dgi_l[VOUT * ROWS];       // [74][48]
    __shared__ float log_l[VOUT];
    __shared__ int   s_tok, s_done;

    const int t   = threadIdx.x;
    const int w   = blockIdx.x;
    const int u   = t >> 4;                    // unit 0..15
    const int sub = t & 15;                    // k-chunk 0..15 (16 floats)
    const int gu  = w * HW + u;                // global unit
    unsigned long long* hx = (unsigned long long*)(ws + WS_HX);

    if (t == 0) { s_done = 0; s_tok = 2; }     // BOS=2
    if (w == 0 && t < STEPS) out[t] = 0;
    if (t < VOUT) fb[t] = fc_b[t];
    for (int idx = t; idx < L * ROWS; idx += 256)
        egi_l[idx] = ws[WS_EGI + w * (L * ROWS) + idx];
    for (int idx = t; idx < VOUT * ROWS; idx += 256)
        dgi_l[idx] = ws[WS_DGI + w * (VOUT * ROWS) + idx];

    // ---- Whh slices: 3 gate rows of unit gu, 16-float k-chunk ----
    float4 wRe[4], wZe[4], wNe[4], wRd[4], wZd[4], wNd[4];
    {
        const float* e0 = enc_Whh + (gu)         * H + sub * 16;
        const float* e1 = enc_Whh + (H + gu)     * H + sub * 16;
        const float* e2 = enc_Whh + (2 * H + gu) * H + sub * 16;
        const float* d0 = dec_Whh + (gu)         * H + sub * 16;
        const float* d1 = dec_Whh + (H + gu)     * H + sub * 16;
        const float* d2 = dec_Whh + (2 * H + gu) * H + sub * 16;
        #pragma unroll
        for (int i = 0; i < 4; ++i) {
            wRe[i] = *(const float4*)(e0 + 4 * i);
            wZe[i] = *(const float4*)(e1 + 4 * i);
            wNe[i] = *(const float4*)(e2 + 4 * i);
            wRd[i] = *(const float4*)(d0 + 4 * i);
            wZd[i] = *(const float4*)(d1 + 4 * i);
            wNd[i] = *(const float4*)(d2 + 4 * i);
        }
    }
    float bRe = 0.f, bZe = 0.f, bNe = 0.f, bRd = 0.f, bZd = 0.f, bNd = 0.f;
    if (sub == 0) {
        bRe = enc_bhh[gu]; bZe = enc_bhh[H + gu]; bNe = enc_bhh[2 * H + gu];
        bRd = dec_bhh[gu]; bZd = dec_bhh[H + gu]; bNd = dec_bhh[2 * H + gu];
    }

    // fc_W in registers: primary row t>>2 chunk t&3; secondary 64+(t>>2) for t<40
    const int rF = t >> 2, pF = t & 3;
    float4 wF[16], wF2[16];
    {
        const float* fp = fc_W + rF * H + pF * 64;
        #pragma unroll
        for (int i = 0; i < 16; ++i) wF[i] = *(const float4*)(fp + 4 * i);
        if (t < 40) {
            const float* fp2 = fc_W + (64 + rF) * H + pF * 64;
            #pragma unroll
            for (int i = 0; i < 16; ++i) wF2[i] = *(const float4*)(fp2 + 4 * i);
        }
    }

    int tok = 2;  // BOS
    for (int s = 0; s <= L + STEPS; ++s) {      // 0..52
        // ---- wait for h^(s): thread t polls its own packed word ----
        {
            const unsigned long long* src = hx + (s & 1) * H + t;
            unsigned long long pk = __hip_atomic_load(src, __ATOMIC_RELAXED,
                                                      __HIP_MEMORY_SCOPE_AGENT);
            while ((unsigned)pk != (unsigned)s) {
                __builtin_amdgcn_s_sleep(1);
                pk = __hip_atomic_load(src, __ATOMIC_RELAXED,
                                       __HIP_MEMORY_SCOPE_AGENT);
            }
            float hv = __uint_as_float((unsigned)(pk >> 32));
            hl[t] = hv; hl[260 + t] = hv; hl[520 + t] = hv; hl[780 + t] = hv;
        }
        __syncthreads();

        // ---- matvec: 3 gate rows x 16 k per thread (tok-independent) ----
        float aR, aZ, aN;
        {
            const float* hb = hl + (sub >> 2) * 260 + sub * 16;  // 2-way max
            float4 h4[4];
            #pragma unroll
            for (int i = 0; i < 4; ++i) h4[i] = *(const float4*)(hb + 4 * i);
            const bool enc = (s < L);
            float r0 = 0.f, z0 = 0.f, n0 = 0.f;
            if (enc) {
                #pragma unroll
                for (int i = 0; i < 4; ++i) {
                    r0 = fmaf(wRe[i].x, h4[i].x, fmaf(wRe[i].y, h4[i].y,
                         fmaf(wRe[i].z, h4[i].z, fmaf(wRe[i].w, h4[i].w, r0))));
                    z0 = fmaf(wZe[i].x, h4[i].x, fmaf(wZe[i].y, h4[i].y,
                         fmaf(wZe[i].z, h4[i].z, fmaf(wZe[i].w, h4[i].w, z0))));
                    n0 = fmaf(wNe[i].x, h4[i].x, fmaf(wNe[i].y, h4[i].y,
                         fmaf(wNe[i].z, h4[i].z, fmaf(wNe[i].w, h4[i].w, n0))));
                }
            } else {
                #pragma unroll
                for (int i = 0; i < 4; ++i) {
                    r0 = fmaf(wRd[i].x, h4[i].x, fmaf(wRd[i].y, h4[i].y,
                         fmaf(wRd[i].z, h4[i].z, fmaf(wRd[i].w, h4[i].w, r0))));
                    z0 = fmaf(wZd[i].x, h4[i].x, fmaf(wZd[i].y, h4[i].y,
                         fmaf(wZd[i].z, h4[i].z, fmaf(wZd[i].w, h4[i].w, z0))));
                    n0 = fmaf(wNd[i].x, h4[i].x, fmaf(wNd[i].y, h4[i].y,
                         fmaf(wNd[i].z, h4[i].z, fmaf(wNd[i].w, h4[i].w, n0))));
                }
            }
            #pragma unroll
            for (int mm = 1; mm < 16; mm <<= 1) {
                r0 += __shfl_xor(r0, mm);
                z0 += __shfl_xor(z0, mm);
                n0 += __shfl_xor(n0, mm);
            }
            aR = r0; aZ = z0; aN = n0;
        }

        const bool dec_out = (s >= L + 1);
        if (dec_out) {
            // ---- logits from registers on h^(s) ----
            const float* hb2 = hl + pF * 324;
            float a0 = 0.f, a1 = 0.f;
            #pragma unroll
            for (int i = 0; i < 16; i += 2) {
                float4 h4a = *(const float4*)(hb2 + 4 * i);
                float4 h4b = *(const float4*)(hb2 + 4 * i + 4);
                a0 = fmaf(wF[i].x, h4a.x, fmaf(wF[i].y, h4a.y,
                      fmaf(wF[i].z, h4a.z, fmaf(wF[i].w, h4a.w, a0))));
                a1 = fmaf(wF[i+1].x, h4b.x, fmaf(wF[i+1].y, h4b.y,
                      fmaf(wF[i+1].z, h4b.z, fmaf(wF[i+1].w, h4b.w, a1))));
            }
            float a = a0 + a1;
            a += __shfl_xor(a, 1); a += __shfl_xor(a, 2);
            if (pF == 0) log_l[rF] = a + fb[rF];
            if (t < 40) {
                float b0 = 0.f, b1 = 0.f;
                #pragma unroll
                for (int i = 0; i < 16; i += 2) {
                    float4 h4a = *(const float4*)(hb2 + 4 * i);
                    float4 h4b = *(const float4*)(hb2 + 4 * i + 4);
                    b0 = fmaf(wF2[i].x, h4a.x, fmaf(wF2[i].y, h4a.y,
                          fmaf(wF2[i].z, h4a.z, fmaf(wF2[i].w, h4a.w, b0))));
                    b1 = fmaf(wF2[i+1].x, h4b.x, fmaf(wF2[i+1].y, h4b.y,
                          fmaf(wF2[i+1].z, h4b.z, fmaf(wF2[i+1].w, h4b.w, b1))));
                }
                float a2 = b0 + b1;
                a2 += __shfl_xor(a2, 1); a2 += __shfl_xor(a2, 2);
                if (pF == 0) log_l[64 + rF] = a2 + fb[64 + rF];
            }
            __syncthreads();

            // ---- argmax (first-index tie-break) on wave 0 ----
            if (t < 64) {
                float v = log_l[t]; int bi = t;
                if (t < VOUT - 64) {
                    float v2 = log_l[64 + t];
                    if (v2 > v) { v = v2; bi = 64 + t; }
                }
                #pragma unroll
                for (int mm = 1; mm < 64; mm <<= 1) {
                    float ov = __shfl_xor(v, mm);
                    int   ob = __shfl_xor(bi, mm);
                    if (ov > v || (ov == v && ob < bi)) { v = ov; bi = ob; }
                }
                if (t == 0) {
                    bool eos = (bi == 3);                    // EOS=3
                    if (w == 0 && !eos) out[s - (L + 1)] = bi;
                    s_tok = bi;
                    if (eos) s_done = 1;
                }
            }
            __syncthreads();
            tok = s_tok;
            if (s_done || s == L + STEPS) break;
        }

        // ---- gates fully in-register on lane sub==0; publish immediately ----
        if (sub == 0) {
            const bool enc = (s < L);
            const float* gi = enc ? (egi_l + s * ROWS) : (dgi_l + tok * ROWS);
            float bR = enc ? bRe : bRd, bZ = enc ? bZe : bZd, bN = enc ? bNe : bNd;
            float rr = sigmoidf_(gi[u]      + aR + bR);
            float zz = sigmoidf_(gi[16 + u] + aZ + bZ);
            float nn = tanhf    (gi[32 + u] + rr * (aN + bN));
            float hn = (1.f - zz) * nn + zz * hl[gu];
            unsigned long long pk =
                ((unsigned long long)__float_as_uint(hn) << 32) |
                (unsigned)(s + 1);
            __hip_atomic_store(hx + ((s + 1) & 1) * H + gu, pk,
                               __ATOMIC_RELAXED, __HIP_MEMORY_SCOPE_AGENT);
        }
        __syncthreads();   // protect hl: this step's reads vs next step's writes
    }
}

extern "C" void kernel_launch(void* const* d_in, const int* in_sizes, int n_in,
                              void* d_out, int out_size, void* d_ws, size_t ws_size,
                              hipStream_t stream) {
    const int*   enc_input = (const int*)  d_in[0];
    const float* enc_emb   = (const float*)d_in[1];
    const float* enc_Wih   = (const float*)d_in[2];
    const float* enc_Whh   = (const float*)d_in[3];
    const float* enc_bih   = (const float*)d_in[4];
    const float* enc_bhh   = (const float*)d_in[5];
    const float* dec_emb   = (const float*)d_in[6];
    const float* dec_Wih   = (const float*)d_in[7];
    const float* dec_Whh   = (const float*)d_in[8];
    const float* dec_bih   = (const float*)d_in[9];
    const float* dec_bhh   = (const float*)d_in[10];
    const float* fc_W      = (const float*)d_in[11];
    const float* fc_b      = (const float*)d_in[12];
    float* ws  = (float*)d_ws;
    int*  outp = (int*)d_out;

    // prep: 3072 enc + 7680 dec wave-tasks, 4 waves/block
    hipLaunchKernelGGL(prep, dim3(2688), dim3(256), 0, stream,
                       enc_input, enc_emb, enc_Wih, enc_bih,
                       dec_emb, dec_Wih, dec_bih, ws);
    hipLaunchKernelGGL(gru_seq, dim3(NP), dim3(256), 0, stream,
                       enc_Whh, enc_bhh, dec_Whh, dec_bhh, fc_W, fc_b,
                       ws, outp);
}